// Round 1
// baseline (556.359 us; speedup 1.0000x reference)
//
#include <hip/hip_runtime.h>
#include <math.h>

// Problem constants
constexpr int Bb = 32;
constexpr int Ll = 1024;
constexpr int DC = 1024;
constexpr int DQ = 1024;
constexpr int Hh = 512;
#define NEG_NUM -10000.0f

// ---------------------------------------------------------------------------
// zero-init score (ws) and expected_ctx (d_out) — both B*1024 floats
// ---------------------------------------------------------------------------
__global__ void zero_kernel(float* __restrict__ a, float* __restrict__ b, int n) {
    int i = blockIdx.x * blockDim.x + threadIdx.x;
    if (i < n) { a[i] = 0.f; b[i] = 0.f; }
}

// ---------------------------------------------------------------------------
// qb[b,h] = sum_c query[b,c] * W1[DC+c, h] + b1[h]
// one thread per (b,h); consecutive threads -> consecutive h -> coalesced W1 rows
// ---------------------------------------------------------------------------
__global__ __launch_bounds__(256) void qb_kernel(const float* __restrict__ query,
                                                 const float* __restrict__ W1,
                                                 const float* __restrict__ b1,
                                                 float* __restrict__ qb) {
    int idx = blockIdx.x * 256 + threadIdx.x;   // b*H + h
    int b = idx >> 9;
    int h = idx & (Hh - 1);
    const float* q = query + (size_t)b * DQ;
    const float* w = W1 + (size_t)DC * Hh + h;
    float a0 = 0.f, a1 = 0.f, a2 = 0.f, a3 = 0.f;
    for (int c = 0; c < DQ; c += 4) {
        a0 += q[c + 0] * w[(size_t)(c + 0) * Hh];
        a1 += q[c + 1] * w[(size_t)(c + 1) * Hh];
        a2 += q[c + 2] * w[(size_t)(c + 2) * Hh];
        a3 += q[c + 3] * w[(size_t)(c + 3) * Hh];
    }
    qb[idx] = (a0 + a1) + (a2 + a3) + b1[h];
}

// ---------------------------------------------------------------------------
// Fused GEMM + tanh + w2 reduction:
//   score[m] += sum_{h in tile} tanh( (ctx @ W1[:DC])[m,h] + qb[b,h] ) * w2[h]
// M = B*L = 32768, N = H = 512, K = DC = 1024.
// Tile 64x64, BK=16, 256 threads, 4x4 microtile per thread.
// N is split across 8 blocks -> partial row sums accumulated via atomicAdd.
// ---------------------------------------------------------------------------
__global__ __launch_bounds__(256) void gemm_score(const float* __restrict__ ctx,
                                                  const float* __restrict__ W1,
                                                  const float* __restrict__ qb,
                                                  const float* __restrict__ w2,
                                                  float* __restrict__ score) {
    __shared__ float As[64][17];   // [m][k], padded
    __shared__ float Bs[16][68];   // [k][n], padded (68*4B = 272B, 16B-aligned rows)

    const int m0 = blockIdx.x * 64;
    const int n0 = blockIdx.y * 64;
    const int tid = threadIdx.x;
    const int tx = tid & 15;        // n-direction (4 cols each)
    const int ty = tid >> 4;        // m-direction (4 rows each)

    float acc[4][4] = {{0.f}};

    const int arow = tid >> 2, akq = tid & 3;       // A staging coords
    const int brow = tid >> 4, bcq = tid & 15;      // B staging coords

    for (int k0 = 0; k0 < DC; k0 += 16) {
        float4 av = *(const float4*)(ctx + (size_t)(m0 + arow) * DC + k0 + akq * 4);
        float4 bv = *(const float4*)(W1 + (size_t)(k0 + brow) * Hh + n0 + bcq * 4);
        As[arow][akq * 4 + 0] = av.x;
        As[arow][akq * 4 + 1] = av.y;
        As[arow][akq * 4 + 2] = av.z;
        As[arow][akq * 4 + 3] = av.w;
        *(float4*)&Bs[brow][bcq * 4] = bv;
        __syncthreads();

#pragma unroll
        for (int kk = 0; kk < 16; ++kk) {
            float a[4], bvv[4];
#pragma unroll
            for (int i = 0; i < 4; ++i) a[i] = As[ty * 4 + i][kk];
            float4 b4 = *(const float4*)&Bs[kk][tx * 4];
            bvv[0] = b4.x; bvv[1] = b4.y; bvv[2] = b4.z; bvv[3] = b4.w;
#pragma unroll
            for (int i = 0; i < 4; ++i)
#pragma unroll
                for (int j = 0; j < 4; ++j)
                    acc[i][j] += a[i] * bvv[j];
        }
        __syncthreads();
    }

    // epilogue: hidden = tanh(acc + qb), partial score = sum_j hidden * w2
    const int b = m0 / Ll;           // 64 | 1024, so whole tile is one batch
    const float* qbb = qb + (size_t)b * Hh;
#pragma unroll
    for (int i = 0; i < 4; ++i) {
        float s = 0.f;
#pragma unroll
        for (int j = 0; j < 4; ++j) {
            int h = n0 + tx * 4 + j;
            s += tanhf(acc[i][j] + qbb[h]) * w2[h];
        }
        // reduce across the 16 tx lanes of this row group
#pragma unroll
        for (int off = 8; off; off >>= 1) s += __shfl_xor(s, off, 16);
        if (tx == 0) atomicAdd(&score[m0 + ty * 4 + i], s);
    }
}

// ---------------------------------------------------------------------------
// scan: p = sigmoid(score + b2, masked, + noise); att_l = p_l * prod_{i<l}(1-p_i)
// one wave (64 lanes) per batch; 16 elements per lane; multiplicative scan.
// ---------------------------------------------------------------------------
__global__ __launch_bounds__(64) void scan_kernel(const float* __restrict__ score,
                                                  const int* __restrict__ mask,
                                                  const float* __restrict__ noise,
                                                  const float* __restrict__ b2p,
                                                  float* __restrict__ att) {
    int b = blockIdx.x;
    int lane = threadIdx.x;
    float b2 = b2p[0];
    int base = b * Ll + lane * 16;

    float p[16], q[16];
    float run = 1.f;
#pragma unroll
    for (int j = 0; j < 16; ++j) {
        int l = base + j;
        float s = score[l] + b2;
        if (mask[l] == 0) s = NEG_NUM;
        s += noise[l];
        float pv = 1.f / (1.f + expf(-s));
        p[j] = pv;
        run *= (1.f - pv);
        q[j] = run;                 // local inclusive product
    }

    // inclusive multiplicative scan of per-lane totals across 64 lanes
    float incl = run;
#pragma unroll
    for (int off = 1; off < 64; off <<= 1) {
        float v = __shfl_up(incl, off, 64);
        if (lane >= off) incl *= v;
    }
    float excl = __shfl_up(incl, 1, 64);
    if (lane == 0) excl = 1.f;

#pragma unroll
    for (int j = 0; j < 16; ++j) {
        float P = excl * (j == 0 ? 1.f : q[j - 1]);
        att[base + j] = p[j] * P;
    }
}

// ---------------------------------------------------------------------------
// expected_ctx[b,c] = sum_l att[b,l] * ctx[b,l,c]
// grid (DC/256, L-splits, B); partials via atomicAdd (out zero-initialized)
// ---------------------------------------------------------------------------
__global__ __launch_bounds__(256) void ectx_kernel(const float* __restrict__ ctx,
                                                   const float* __restrict__ att,
                                                   float* __restrict__ out) {
    int b = blockIdx.z;
    int c = blockIdx.x * 256 + threadIdx.x;
    int l0 = blockIdx.y * 128;
    const float* cb = ctx + ((size_t)b * Ll) * DC + c;
    const float* ab = att + (size_t)b * Ll;
    float a0 = 0.f, a1 = 0.f, a2 = 0.f, a3 = 0.f;
    for (int l = l0; l < l0 + 128; l += 4) {
        a0 += ab[l + 0] * cb[(size_t)(l + 0) * DC];
        a1 += ab[l + 1] * cb[(size_t)(l + 1) * DC];
        a2 += ab[l + 2] * cb[(size_t)(l + 2) * DC];
        a3 += ab[l + 3] * cb[(size_t)(l + 3) * DC];
    }
    atomicAdd(&out[(size_t)b * DC + c], (a0 + a1) + (a2 + a3));
}

// ---------------------------------------------------------------------------
extern "C" void kernel_launch(void* const* d_in, const int* in_sizes, int n_in,
                              void* d_out, int out_size, void* d_ws, size_t ws_size,
                              hipStream_t stream) {
    const float* ctx   = (const float*)d_in[0];
    const float* query = (const float*)d_in[1];
    const int*   mask  = (const int*)d_in[2];
    const float* noise = (const float*)d_in[3];
    const float* W1    = (const float*)d_in[4];
    const float* b1    = (const float*)d_in[5];
    const float* w2    = (const float*)d_in[6];
    const float* b2    = (const float*)d_in[7];

    float* out_ctx = (float*)d_out;                 // [B, DC]
    float* out_att = (float*)d_out + Bb * DC;       // [B, L]

    float* score = (float*)d_ws;                    // [B*L]
    float* qb    = score + Bb * Ll;                 // [B*H]

    // zero score + expected_ctx (both 32768 floats)
    zero_kernel<<<(Bb * Ll) / 256, 256, 0, stream>>>(score, out_ctx, Bb * Ll);

    // query @ W1[DC:] + b1
    qb_kernel<<<(Bb * Hh) / 256, 256, 0, stream>>>(query, W1, b1, qb);

    // fused big GEMM + tanh + w2 reduction -> score
    gemm_score<<<dim3((Bb * Ll) / 64, Hh / 64), 256, 0, stream>>>(ctx, W1, qb, w2, score);

    // sigmoid / mask / noise / monotonic scan -> att (second output)
    scan_kernel<<<Bb, 64, 0, stream>>>(score, mask, noise, b2, out_att);

    // expected_ctx = att @ ctx (first output)
    ectx_kernel<<<dim3(DC / 256, Ll / 128, Bb), 256, 0, stream>>>(ctx, out_att, out_ctx);
}

// Round 2
// 150.780 us; speedup vs baseline: 3.6899x; 3.6899x over previous
//
#include <hip/hip_runtime.h>
#include <hip/hip_bf16.h>
#include <math.h>

// Problem constants
constexpr int Bb = 32;
constexpr int Ll = 1024;
constexpr int DC = 1024;
constexpr int DQ = 1024;
constexpr int Hh = 512;
#define NEG_NUM -10000.0f

typedef __attribute__((ext_vector_type(8))) short bf16x8;
typedef __attribute__((ext_vector_type(4))) float f32x4;

#define GLOAD_LDS16(g, l)                                                  \
    __builtin_amdgcn_global_load_lds(                                      \
        (const __attribute__((address_space(1))) void*)(g),                \
        (__attribute__((address_space(3))) void*)(l), 16, 0, 0)

__device__ inline unsigned short f2bf(float f) {           // RNE f32->bf16
    unsigned int x = __float_as_uint(f);
    unsigned int r = (x + 0x7FFFu + ((x >> 16) & 1u)) >> 16;
    return (unsigned short)r;
}
__device__ inline float bfu(unsigned short u) {            // bf16 bits -> f32 (exact)
    return __uint_as_float(((unsigned int)u) << 16);
}

// ---------------------------------------------------------------------------
// zero-init score (ws) and expected_ctx (d_out) — both B*1024 floats
// ---------------------------------------------------------------------------
__global__ void zero_kernel(float* __restrict__ a, float* __restrict__ b, int n) {
    int i = blockIdx.x * blockDim.x + threadIdx.x;
    if (i < n) { a[i] = 0.f; b[i] = 0.f; }
}

// ---------------------------------------------------------------------------
// ctx fp32 -> bf16, 8 elements/thread, fully vectorized
// ---------------------------------------------------------------------------
__global__ __launch_bounds__(256) void cvt_ctx_kernel(const float* __restrict__ in,
                                                      unsigned short* __restrict__ out) {
    size_t i = (size_t)(blockIdx.x * 256 + threadIdx.x) * 8;
    float4 v0 = *(const float4*)(in + i);
    float4 v1 = *(const float4*)(in + i + 4);
    union { unsigned short us[8]; uint4 v; } o;
    o.us[0] = f2bf(v0.x); o.us[1] = f2bf(v0.y); o.us[2] = f2bf(v0.z); o.us[3] = f2bf(v0.w);
    o.us[4] = f2bf(v1.x); o.us[5] = f2bf(v1.y); o.us[6] = f2bf(v1.z); o.us[7] = f2bf(v1.w);
    *(uint4*)(out + i) = o.v;
}

// ---------------------------------------------------------------------------
// W1[:DC] (1024 x 512 row-major) -> W1T bf16 (512 x 1024 row-major)
// output-coalesced; input served by L2 (2 MB)
// ---------------------------------------------------------------------------
__global__ __launch_bounds__(256) void cvt_w1t_kernel(const float* __restrict__ W1,
                                                      unsigned short* __restrict__ w1t) {
    int idx = blockIdx.x * 256 + threadIdx.x;   // n*1024 + k
    int n = idx >> 10, k = idx & 1023;
    w1t[idx] = f2bf(W1[(size_t)k * Hh + n]);
}

// ---------------------------------------------------------------------------
// qb[b,h] = sum_c query[b,c] * W1[DC+c, h] + b1[h]   (fp32, tiny)
// ---------------------------------------------------------------------------
__global__ __launch_bounds__(256) void qb_kernel(const float* __restrict__ query,
                                                 const float* __restrict__ W1,
                                                 const float* __restrict__ b1,
                                                 float* __restrict__ qb) {
    int idx = blockIdx.x * 256 + threadIdx.x;   // b*H + h
    int b = idx >> 9;
    int h = idx & (Hh - 1);
    const float* q = query + (size_t)b * DQ;
    const float* w = W1 + (size_t)DC * Hh + h;
    float a0 = 0.f, a1 = 0.f, a2 = 0.f, a3 = 0.f;
    for (int c = 0; c < DQ; c += 4) {
        a0 += q[c + 0] * w[(size_t)(c + 0) * Hh];
        a1 += q[c + 1] * w[(size_t)(c + 1) * Hh];
        a2 += q[c + 2] * w[(size_t)(c + 2) * Hh];
        a3 += q[c + 3] * w[(size_t)(c + 3) * Hh];
    }
    qb[idx] = (a0 + a1) + (a2 + a3) + b1[h];
}

// ---------------------------------------------------------------------------
// MFMA GEMM + tanh + w2 reduction.
//   M = B*L = 32768 (rows of ctx_bf16 [M][1024]),
//   N = H  = 512    (rows of w1t     [N][1024]),
//   K = DC = 1024.
// 128x128 tile, BK=32, 256 thr (4 waves 2x2), 4x4 frags of 16x16x32 per wave.
// global_load_lds width-16 staging, linear LDS (T2 null at 2-phase per guide).
// Epilogue: score[row] += sum_col tanh(acc + qb[col]) * w2[col]  (atomicAdd).
// ---------------------------------------------------------------------------
__global__ __launch_bounds__(256) void gemm_mfma(const unsigned short* __restrict__ ctxb,
                                                 const unsigned short* __restrict__ w1t,
                                                 const float* __restrict__ qb,
                                                 const float* __restrict__ w2,
                                                 float* __restrict__ score) {
    __shared__ unsigned short As[128 * 32];   // [m][k] 64 B rows
    __shared__ unsigned short Bs[128 * 32];   // [n][k] 64 B rows

    const int m0 = blockIdx.x * 128;
    const int n0 = blockIdx.y * 128;
    const int tid = threadIdx.x;
    const int w = tid >> 6, lane = tid & 63;
    const int wr = w >> 1, wc = w & 1;
    const int lr = lane & 15, lk = lane >> 4;

    const char* ctxB = (const char*)ctxb;
    const char* w1tB = (const char*)w1t;

    f32x4 acc[4][4];
#pragma unroll
    for (int m = 0; m < 4; ++m)
#pragma unroll
        for (int n = 0; n < 4; ++n) acc[m][n] = (f32x4){0.f, 0.f, 0.f, 0.f};

    const char* Abase = (const char*)As + (wr * 64 + lr) * 64 + lk * 16;
    const char* Bbase = (const char*)Bs + (wc * 64 + lr) * 64 + lk * 16;

    for (int k0 = 0; k0 < DC; k0 += 32) {
#pragma unroll
        for (int it = 0; it < 2; ++it) {
            int cbyte = w * 2048 + it * 1024;          // wave-uniform LDS base
            int c = cbyte + lane * 16;                 // this lane's tile byte
            int row = c >> 6, colb = c & 63;
            GLOAD_LDS16(ctxB + (size_t)(m0 + row) * 2048 + k0 * 2 + colb,
                        (char*)As + cbyte);
            GLOAD_LDS16(w1tB + (size_t)(n0 + row) * 2048 + k0 * 2 + colb,
                        (char*)Bs + cbyte);
        }
        __syncthreads();

        bf16x8 a[4], b[4];
#pragma unroll
        for (int m = 0; m < 4; ++m) a[m] = *(const bf16x8*)(Abase + m * 16 * 64);
#pragma unroll
        for (int n = 0; n < 4; ++n) b[n] = *(const bf16x8*)(Bbase + n * 16 * 64);
#pragma unroll
        for (int m = 0; m < 4; ++m)
#pragma unroll
            for (int n = 0; n < 4; ++n)
                acc[m][n] = __builtin_amdgcn_mfma_f32_16x16x32_bf16(a[m], b[n], acc[m][n], 0, 0, 0);
        __syncthreads();
    }

    // Epilogue. C/D layout: col = n*16 + lr, row = m*16 + lk*4 + r.
    const int bq = m0 >> 10;                     // 128 | 1024 -> one batch per block
    const float* qbb = qb + (size_t)bq * Hh;
#pragma unroll
    for (int m = 0; m < 4; ++m) {
        float s0 = 0.f, s1 = 0.f, s2 = 0.f, s3 = 0.f;
#pragma unroll
        for (int n = 0; n < 4; ++n) {
            int col = n0 + wc * 64 + n * 16 + lr;
            float wv = w2[col];
            float qv = qbb[col];
            s0 += tanhf(acc[m][n][0] + qv) * wv;
            s1 += tanhf(acc[m][n][1] + qv) * wv;
            s2 += tanhf(acc[m][n][2] + qv) * wv;
            s3 += tanhf(acc[m][n][3] + qv) * wv;
        }
#pragma unroll
        for (int off = 8; off; off >>= 1) {
            s0 += __shfl_xor(s0, off, 16);
            s1 += __shfl_xor(s1, off, 16);
            s2 += __shfl_xor(s2, off, 16);
            s3 += __shfl_xor(s3, off, 16);
        }
        if (lr == 0) {
            int row = m0 + wr * 64 + m * 16 + lk * 4;
            atomicAdd(&score[row + 0], s0);
            atomicAdd(&score[row + 1], s1);
            atomicAdd(&score[row + 2], s2);
            atomicAdd(&score[row + 3], s3);
        }
    }
}

// ---------------------------------------------------------------------------
// fp32 fallback GEMM (round-1 kernel) — used only if ws too small for bf16 path
// ---------------------------------------------------------------------------
__global__ __launch_bounds__(256) void gemm_score_f32(const float* __restrict__ ctx,
                                                      const float* __restrict__ W1,
                                                      const float* __restrict__ qb,
                                                      const float* __restrict__ w2,
                                                      float* __restrict__ score) {
    __shared__ float As[64][17];
    __shared__ float Bs[16][68];
    const int m0 = blockIdx.x * 64;
    const int n0 = blockIdx.y * 64;
    const int tid = threadIdx.x;
    const int tx = tid & 15;
    const int ty = tid >> 4;
    float acc[4][4] = {{0.f}};
    const int arow = tid >> 2, akq = tid & 3;
    const int brow = tid >> 4, bcq = tid & 15;
    for (int k0 = 0; k0 < DC; k0 += 16) {
        float4 av = *(const float4*)(ctx + (size_t)(m0 + arow) * DC + k0 + akq * 4);
        float4 bv = *(const float4*)(W1 + (size_t)(k0 + brow) * Hh + n0 + bcq * 4);
        As[arow][akq * 4 + 0] = av.x; As[arow][akq * 4 + 1] = av.y;
        As[arow][akq * 4 + 2] = av.z; As[arow][akq * 4 + 3] = av.w;
        *(float4*)&Bs[brow][bcq * 4] = bv;
        __syncthreads();
#pragma unroll
        for (int kk = 0; kk < 16; ++kk) {
            float a[4], bvv[4];
#pragma unroll
            for (int i = 0; i < 4; ++i) a[i] = As[ty * 4 + i][kk];
            float4 b4 = *(const float4*)&Bs[kk][tx * 4];
            bvv[0] = b4.x; bvv[1] = b4.y; bvv[2] = b4.z; bvv[3] = b4.w;
#pragma unroll
            for (int i = 0; i < 4; ++i)
#pragma unroll
                for (int j = 0; j < 4; ++j) acc[i][j] += a[i] * bvv[j];
        }
        __syncthreads();
    }
    const int b = m0 / Ll;
    const float* qbb = qb + (size_t)b * Hh;
#pragma unroll
    for (int i = 0; i < 4; ++i) {
        float s = 0.f;
#pragma unroll
        for (int j = 0; j < 4; ++j) {
            int h = n0 + tx * 4 + j;
            s += tanhf(acc[i][j] + qbb[h]) * w2[h];
        }
#pragma unroll
        for (int off = 8; off; off >>= 1) s += __shfl_xor(s, off, 16);
        if (tx == 0) atomicAdd(&score[m0 + ty * 4 + i], s);
    }
}

// ---------------------------------------------------------------------------
// scan: p = sigmoid(score + b2, masked, + noise); att_l = p_l * prod_{i<l}(1-p_i)
// ---------------------------------------------------------------------------
__global__ __launch_bounds__(64) void scan_kernel(const float* __restrict__ score,
                                                  const int* __restrict__ mask,
                                                  const float* __restrict__ noise,
                                                  const float* __restrict__ b2p,
                                                  float* __restrict__ att) {
    int b = blockIdx.x;
    int lane = threadIdx.x;
    float b2 = b2p[0];
    int base = b * Ll + lane * 16;

    float p[16], q[16];
    float run = 1.f;
#pragma unroll
    for (int j = 0; j < 16; ++j) {
        int l = base + j;
        float s = score[l] + b2;
        if (mask[l] == 0) s = NEG_NUM;
        s += noise[l];
        float pv = 1.f / (1.f + expf(-s));
        p[j] = pv;
        run *= (1.f - pv);
        q[j] = run;
    }
    float incl = run;
#pragma unroll
    for (int off = 1; off < 64; off <<= 1) {
        float v = __shfl_up(incl, off, 64);
        if (lane >= off) incl *= v;
    }
    float excl = __shfl_up(incl, 1, 64);
    if (lane == 0) excl = 1.f;
#pragma unroll
    for (int j = 0; j < 16; ++j) {
        float P = excl * (j == 0 ? 1.f : q[j - 1]);
        att[base + j] = p[j] * P;
    }
}

// ---------------------------------------------------------------------------
// expected_ctx[b,c] = sum_l att[b,l] * ctx[b,l,c]   (bf16 ctx, 4 c per thread)
// ---------------------------------------------------------------------------
__global__ __launch_bounds__(256) void ectx_bf16_kernel(const unsigned short* __restrict__ ctxb,
                                                        const float* __restrict__ att,
                                                        float* __restrict__ out) {
    int b = blockIdx.z;
    int c4 = threadIdx.x;                 // c = c4*4
    int l0 = blockIdx.y * 128;
    const unsigned short* cb = ctxb + ((size_t)b * Ll + l0) * DC + c4 * 4;
    const float* ab = att + (size_t)b * Ll + l0;
    float a0 = 0.f, a1 = 0.f, a2 = 0.f, a3 = 0.f;
    for (int l = 0; l < 128; ++l) {
        float av = ab[l];
        ushort4 v = *(const ushort4*)(cb + (size_t)l * DC);
        a0 += av * bfu(v.x); a1 += av * bfu(v.y);
        a2 += av * bfu(v.z); a3 += av * bfu(v.w);
    }
    float* o = out + (size_t)b * DC + c4 * 4;
    atomicAdd(o + 0, a0); atomicAdd(o + 1, a1);
    atomicAdd(o + 2, a2); atomicAdd(o + 3, a3);
}

__global__ __launch_bounds__(256) void ectx_f32_kernel(const float* __restrict__ ctx,
                                                       const float* __restrict__ att,
                                                       float* __restrict__ out) {
    int b = blockIdx.z;
    int c = blockIdx.x * 256 + threadIdx.x;
    int l0 = blockIdx.y * 128;
    const float* cb = ctx + ((size_t)b * Ll) * DC + c;
    const float* ab = att + (size_t)b * Ll;
    float a0 = 0.f, a1 = 0.f, a2 = 0.f, a3 = 0.f;
    for (int l = l0; l < l0 + 128; l += 4) {
        a0 += ab[l + 0] * cb[(size_t)(l + 0) * DC];
        a1 += ab[l + 1] * cb[(size_t)(l + 1) * DC];
        a2 += ab[l + 2] * cb[(size_t)(l + 2) * DC];
        a3 += ab[l + 3] * cb[(size_t)(l + 3) * DC];
    }
    atomicAdd(&out[(size_t)b * DC + c], (a0 + a1) + (a2 + a3));
}

// ---------------------------------------------------------------------------
extern "C" void kernel_launch(void* const* d_in, const int* in_sizes, int n_in,
                              void* d_out, int out_size, void* d_ws, size_t ws_size,
                              hipStream_t stream) {
    const float* ctx   = (const float*)d_in[0];
    const float* query = (const float*)d_in[1];
    const int*   mask  = (const int*)d_in[2];
    const float* noise = (const float*)d_in[3];
    const float* W1    = (const float*)d_in[4];
    const float* b1    = (const float*)d_in[5];
    const float* w2    = (const float*)d_in[6];
    const float* b2    = (const float*)d_in[7];

    float* out_ctx = (float*)d_out;                 // [B, DC]
    float* out_att = (float*)d_out + Bb * DC;       // [B, L]

    char* ws = (char*)d_ws;
    float* score = (float*)ws;                                   // 131072 B
    float* qb    = (float*)(ws + 131072);                        //  65536 B
    unsigned short* w1t  = (unsigned short*)(ws + 196608);       // 1 MiB
    unsigned short* ctxb = (unsigned short*)(ws + 1245184);      // 64 MiB
    const size_t NEED = 1245184 + (size_t)Bb * Ll * DC * 2;      // ~68.4 MB

    // zero score + expected_ctx (both 32768 floats)
    zero_kernel<<<(Bb * Ll) / 256, 256, 0, stream>>>(score, out_ctx, Bb * Ll);
    // query @ W1[DC:] + b1
    qb_kernel<<<(Bb * Hh) / 256, 256, 0, stream>>>(query, W1, b1, qb);

    if (ws_size >= NEED) {
        // bf16 conversions
        cvt_ctx_kernel<<<(Bb * Ll * DC) / (256 * 8), 256, 0, stream>>>(ctx, ctxb);
        cvt_w1t_kernel<<<(Hh * DC) / 256, 256, 0, stream>>>(W1, w1t);
        // MFMA GEMM + tanh + w2 -> score
        gemm_mfma<<<dim3((Bb * Ll) / 128, Hh / 128), 256, 0, stream>>>(ctxb, w1t, qb, w2, score);
        // sigmoid/mask/noise/scan -> att
        scan_kernel<<<Bb, 64, 0, stream>>>(score, mask, noise, b2, out_att);
        // expected_ctx = att @ ctx  (bf16 ctx)
        ectx_bf16_kernel<<<dim3(1, Ll / 128, Bb), 256, 0, stream>>>(ctxb, out_att, out_ctx);
    } else {
        gemm_score_f32<<<dim3((Bb * Ll) / 64, Hh / 64), 256, 0, stream>>>(ctx, W1, qb, w2, score);
        scan_kernel<<<Bb, 64, 0, stream>>>(score, mask, noise, b2, out_att);
        ectx_f32_kernel<<<dim3(DC / 256, Ll / 128, Bb), 256, 0, stream>>>(ctx, out_att, out_ctx);
    }
}

// Round 3
// 124.318 us; speedup vs baseline: 4.4753x; 1.2129x over previous
//
#include <hip/hip_runtime.h>
#include <hip/hip_bf16.h>
#include <math.h>

// Problem constants
constexpr int Bb = 32;
constexpr int Ll = 1024;
constexpr int DC = 1024;
constexpr int DQ = 1024;
constexpr int Hh = 512;
#define NEG_NUM -10000.0f

typedef __attribute__((ext_vector_type(8))) short bf16x8;
typedef __attribute__((ext_vector_type(4))) float f32x4;

#define GLOAD_LDS16(g, l)                                                  \
    __builtin_amdgcn_global_load_lds(                                      \
        (const __attribute__((address_space(1))) void*)(g),                \
        (__attribute__((address_space(3))) void*)(l), 16, 0, 0)

__device__ inline unsigned short f2bf(float f) {           // RNE f32->bf16
    unsigned int x = __float_as_uint(f);
    unsigned int r = (x + 0x7FFFu + ((x >> 16) & 1u)) >> 16;
    return (unsigned short)r;
}
__device__ inline float bfu(unsigned short u) {            // bf16 bits -> f32 (exact)
    return __uint_as_float(((unsigned int)u) << 16);
}

// ---------------------------------------------------------------------------
// prep: blocks [0,2048): W1[:DC] (1024x512) -> w1t bf16 (512x1024, transposed)
//       blocks [2048,2176): zero score + out_ctx (32768 floats each)
// ---------------------------------------------------------------------------
__global__ __launch_bounds__(256) void prep_kernel(const float* __restrict__ W1,
                                                   unsigned short* __restrict__ w1t,
                                                   float* __restrict__ score,
                                                   float* __restrict__ out_ctx) {
    int bid = blockIdx.x;
    if (bid < 2048) {
        int idx = bid * 256 + threadIdx.x;   // n*1024 + k
        int n = idx >> 10, k = idx & 1023;
        w1t[idx] = f2bf(W1[(size_t)k * Hh + n]);
    } else {
        int i = (bid - 2048) * 256 + threadIdx.x;   // < 32768
        score[i] = 0.f;
        out_ctx[i] = 0.f;
    }
}

// ---------------------------------------------------------------------------
// ctx fp32 -> bf16, 8 elements/thread, fully vectorized (BW-bound, ~32 us)
// ---------------------------------------------------------------------------
__global__ __launch_bounds__(256) void cvt_ctx_kernel(const float* __restrict__ in,
                                                      unsigned short* __restrict__ out) {
    size_t i = (size_t)(blockIdx.x * 256 + threadIdx.x) * 8;
    float4 v0 = *(const float4*)(in + i);
    float4 v1 = *(const float4*)(in + i + 4);
    union { unsigned short us[8]; uint4 v; } o;
    o.us[0] = f2bf(v0.x); o.us[1] = f2bf(v0.y); o.us[2] = f2bf(v0.z); o.us[3] = f2bf(v0.w);
    o.us[4] = f2bf(v1.x); o.us[5] = f2bf(v1.y); o.us[6] = f2bf(v1.z); o.us[7] = f2bf(v1.w);
    *(uint4*)(out + i) = o.v;
}

// ---------------------------------------------------------------------------
// qb[b,h] = sum_c query[b,c] * W1[DC+c, h] + b1[h]
// grid 256 blocks (32 b x 8 h-groups of 64), 256 thr: j = tid>>6 owns a
// 256-wide K-chunk; loads coalesced over h (consecutive lanes), query loads
// wave-uniform (scalar). LDS combine across the 4 waves.
// ---------------------------------------------------------------------------
__global__ __launch_bounds__(256) void qb_kernel(const float* __restrict__ query,
                                                 const float* __restrict__ W1,
                                                 const float* __restrict__ b1,
                                                 float* __restrict__ qb) {
    __shared__ float red[4][64];
    const int b  = blockIdx.x >> 3;
    const int hg = blockIdx.x & 7;
    const int hl = threadIdx.x & 63;
    const int j  = threadIdx.x >> 6;
    const int h  = hg * 64 + hl;
    const float* q = query + (size_t)b * DQ + j * 256;
    const float* w = W1 + (size_t)(DC + j * 256) * Hh + h;
    float a0 = 0.f, a1 = 0.f, a2 = 0.f, a3 = 0.f;
#pragma unroll 4
    for (int c = 0; c < 256; c += 4) {
        a0 += q[c + 0] * w[(size_t)(c + 0) * Hh];
        a1 += q[c + 1] * w[(size_t)(c + 1) * Hh];
        a2 += q[c + 2] * w[(size_t)(c + 2) * Hh];
        a3 += q[c + 3] * w[(size_t)(c + 3) * Hh];
    }
    red[j][hl] = (a0 + a1) + (a2 + a3);
    __syncthreads();
    if (j == 0)
        qb[(size_t)b * Hh + h] = red[0][hl] + red[1][hl] + red[2][hl] + red[3][hl] + b1[h];
}

// ---------------------------------------------------------------------------
// MFMA GEMM + tanh + w2 reduction (m97 structure, 128x128, BK=32, verified R2)
// ---------------------------------------------------------------------------
__global__ __launch_bounds__(256) void gemm_mfma(const unsigned short* __restrict__ ctxb,
                                                 const unsigned short* __restrict__ w1t,
                                                 const float* __restrict__ qb,
                                                 const float* __restrict__ w2,
                                                 float* __restrict__ score) {
    __shared__ unsigned short As[128 * 32];   // [m][k] 64 B rows
    __shared__ unsigned short Bs[128 * 32];   // [n][k] 64 B rows

    const int m0 = blockIdx.x * 128;
    const int n0 = blockIdx.y * 128;
    const int tid = threadIdx.x;
    const int w = tid >> 6, lane = tid & 63;
    const int wr = w >> 1, wc = w & 1;
    const int lr = lane & 15, lk = lane >> 4;

    const char* ctxB = (const char*)ctxb;
    const char* w1tB = (const char*)w1t;

    f32x4 acc[4][4];
#pragma unroll
    for (int m = 0; m < 4; ++m)
#pragma unroll
        for (int n = 0; n < 4; ++n) acc[m][n] = (f32x4){0.f, 0.f, 0.f, 0.f};

    const char* Abase = (const char*)As + (wr * 64 + lr) * 64 + lk * 16;
    const char* Bbase = (const char*)Bs + (wc * 64 + lr) * 64 + lk * 16;

    for (int k0 = 0; k0 < DC; k0 += 32) {
#pragma unroll
        for (int it = 0; it < 2; ++it) {
            int cbyte = w * 2048 + it * 1024;          // wave-uniform LDS base
            int c = cbyte + lane * 16;                 // this lane's tile byte
            int row = c >> 6, colb = c & 63;
            GLOAD_LDS16(ctxB + (size_t)(m0 + row) * 2048 + k0 * 2 + colb,
                        (char*)As + cbyte);
            GLOAD_LDS16(w1tB + (size_t)(n0 + row) * 2048 + k0 * 2 + colb,
                        (char*)Bs + cbyte);
        }
        __syncthreads();

        bf16x8 a[4], b[4];
#pragma unroll
        for (int m = 0; m < 4; ++m) a[m] = *(const bf16x8*)(Abase + m * 16 * 64);
#pragma unroll
        for (int n = 0; n < 4; ++n) b[n] = *(const bf16x8*)(Bbase + n * 16 * 64);
#pragma unroll
        for (int m = 0; m < 4; ++m)
#pragma unroll
            for (int n = 0; n < 4; ++n)
                acc[m][n] = __builtin_amdgcn_mfma_f32_16x16x32_bf16(a[m], b[n], acc[m][n], 0, 0, 0);
        __syncthreads();
    }

    // Epilogue. C/D layout: col = n*16 + lr, row = m*16 + lk*4 + r.
    const int bq = m0 >> 10;                     // 128 | 1024 -> one batch per block
    const float* qbb = qb + (size_t)bq * Hh;
#pragma unroll
    for (int m = 0; m < 4; ++m) {
        float s0 = 0.f, s1 = 0.f, s2 = 0.f, s3 = 0.f;
#pragma unroll
        for (int n = 0; n < 4; ++n) {
            int col = n0 + wc * 64 + n * 16 + lr;
            float wv = w2[col];
            float qv = qbb[col];
            s0 += tanhf(acc[m][n][0] + qv) * wv;
            s1 += tanhf(acc[m][n][1] + qv) * wv;
            s2 += tanhf(acc[m][n][2] + qv) * wv;
            s3 += tanhf(acc[m][n][3] + qv) * wv;
        }
#pragma unroll
        for (int off = 8; off; off >>= 1) {
            s0 += __shfl_xor(s0, off, 16);
            s1 += __shfl_xor(s1, off, 16);
            s2 += __shfl_xor(s2, off, 16);
            s3 += __shfl_xor(s3, off, 16);
        }
        if (lr == 0) {
            int row = m0 + wr * 64 + m * 16 + lk * 4;
            atomicAdd(&score[row + 0], s0);
            atomicAdd(&score[row + 1], s1);
            atomicAdd(&score[row + 2], s2);
            atomicAdd(&score[row + 3], s3);
        }
    }
}

// ---------------------------------------------------------------------------
// scan: p = sigmoid(score + b2, masked, + noise); att_l = p_l * prod_{i<l}(1-p_i)
// ---------------------------------------------------------------------------
__global__ __launch_bounds__(64) void scan_kernel(const float* __restrict__ score,
                                                  const int* __restrict__ mask,
                                                  const float* __restrict__ noise,
                                                  const float* __restrict__ b2p,
                                                  float* __restrict__ att) {
    int b = blockIdx.x;
    int lane = threadIdx.x;
    float b2 = b2p[0];
    int base = b * Ll + lane * 16;

    float p[16], q[16];
    float run = 1.f;
#pragma unroll
    for (int j = 0; j < 16; ++j) {
        int l = base + j;
        float s = score[l] + b2;
        if (mask[l] == 0) s = NEG_NUM;
        s += noise[l];
        float pv = 1.f / (1.f + expf(-s));
        p[j] = pv;
        run *= (1.f - pv);
        q[j] = run;
    }
    float incl = run;
#pragma unroll
    for (int off = 1; off < 64; off <<= 1) {
        float v = __shfl_up(incl, off, 64);
        if (lane >= off) incl *= v;
    }
    float excl = __shfl_up(incl, 1, 64);
    if (lane == 0) excl = 1.f;
#pragma unroll
    for (int j = 0; j < 16; ++j) {
        float P = excl * (j == 0 ? 1.f : q[j - 1]);
        att[base + j] = p[j] * P;
    }
}

// ---------------------------------------------------------------------------
// expected_ctx[b,c] = sum_l att[b,l] * ctx[b,l,c]   (bf16 ctx, 4 c per thread)
// ---------------------------------------------------------------------------
__global__ __launch_bounds__(256) void ectx_bf16_kernel(const unsigned short* __restrict__ ctxb,
                                                        const float* __restrict__ att,
                                                        float* __restrict__ out) {
    int b = blockIdx.z;
    int c4 = threadIdx.x;                 // c = c4*4
    int l0 = blockIdx.y * 128;
    const unsigned short* cb = ctxb + ((size_t)b * Ll + l0) * DC + c4 * 4;
    const float* ab = att + (size_t)b * Ll + l0;
    float a0 = 0.f, a1 = 0.f, a2 = 0.f, a3 = 0.f;
    for (int l = 0; l < 128; ++l) {
        float av = ab[l];
        ushort4 v = *(const ushort4*)(cb + (size_t)l * DC);
        a0 += av * bfu(v.x); a1 += av * bfu(v.y);
        a2 += av * bfu(v.z); a3 += av * bfu(v.w);
    }
    float* o = out + (size_t)b * DC + c4 * 4;
    atomicAdd(o + 0, a0); atomicAdd(o + 1, a1);
    atomicAdd(o + 2, a2); atomicAdd(o + 3, a3);
}

// ---------------------------------------------------------------------------
// fp32 fallback path (only if ws too small for bf16 staging)
// ---------------------------------------------------------------------------
__global__ __launch_bounds__(256) void gemm_score_f32(const float* __restrict__ ctx,
                                                      const float* __restrict__ W1,
                                                      const float* __restrict__ qb,
                                                      const float* __restrict__ w2,
                                                      float* __restrict__ score) {
    __shared__ float As[64][17];
    __shared__ float Bs[16][68];
    const int m0 = blockIdx.x * 64;
    const int n0 = blockIdx.y * 64;
    const int tid = threadIdx.x;
    const int tx = tid & 15;
    const int ty = tid >> 4;
    float acc[4][4] = {{0.f}};
    const int arow = tid >> 2, akq = tid & 3;
    const int brow = tid >> 4, bcq = tid & 15;
    for (int k0 = 0; k0 < DC; k0 += 16) {
        float4 av = *(const float4*)(ctx + (size_t)(m0 + arow) * DC + k0 + akq * 4);
        float4 bv = *(const float4*)(W1 + (size_t)(k0 + brow) * Hh + n0 + bcq * 4);
        As[arow][akq * 4 + 0] = av.x; As[arow][akq * 4 + 1] = av.y;
        As[arow][akq * 4 + 2] = av.z; As[arow][akq * 4 + 3] = av.w;
        *(float4*)&Bs[brow][bcq * 4] = bv;
        __syncthreads();
#pragma unroll
        for (int kk = 0; kk < 16; ++kk) {
            float a[4], bvv[4];
#pragma unroll
            for (int i = 0; i < 4; ++i) a[i] = As[ty * 4 + i][kk];
            float4 b4 = *(const float4*)&Bs[kk][tx * 4];
            bvv[0] = b4.x; bvv[1] = b4.y; bvv[2] = b4.z; bvv[3] = b4.w;
#pragma unroll
            for (int i = 0; i < 4; ++i)
#pragma unroll
                for (int j = 0; j < 4; ++j) acc[i][j] += a[i] * bvv[j];
        }
        __syncthreads();
    }
    const int b = m0 / Ll;
    const float* qbb = qb + (size_t)b * Hh;
#pragma unroll
    for (int i = 0; i < 4; ++i) {
        float s = 0.f;
#pragma unroll
        for (int j = 0; j < 4; ++j) {
            int h = n0 + tx * 4 + j;
            s += tanhf(acc[i][j] + qbb[h]) * w2[h];
        }
#pragma unroll
        for (int off = 8; off; off >>= 1) s += __shfl_xor(s, off, 16);
        if (tx == 0) atomicAdd(&score[m0 + ty * 4 + i], s);
    }
}

__global__ __launch_bounds__(256) void ectx_f32_kernel(const float* __restrict__ ctx,
                                                       const float* __restrict__ att,
                                                       float* __restrict__ out) {
    int b = blockIdx.z;
    int c = blockIdx.x * 256 + threadIdx.x;
    int l0 = blockIdx.y * 128;
    const float* cb = ctx + ((size_t)b * Ll) * DC + c;
    const float* ab = att + (size_t)b * Ll;
    float a0 = 0.f, a1 = 0.f, a2 = 0.f, a3 = 0.f;
    for (int l = l0; l < l0 + 128; l += 4) {
        a0 += ab[l + 0] * cb[(size_t)(l + 0) * DC];
        a1 += ab[l + 1] * cb[(size_t)(l + 1) * DC];
        a2 += ab[l + 2] * cb[(size_t)(l + 2) * DC];
        a3 += ab[l + 3] * cb[(size_t)(l + 3) * DC];
    }
    atomicAdd(&out[(size_t)b * DC + c], (a0 + a1) + (a2 + a3));
}

__global__ void zero2_kernel(float* __restrict__ a, float* __restrict__ b, int n) {
    int i = blockIdx.x * blockDim.x + threadIdx.x;
    if (i < n) { a[i] = 0.f; b[i] = 0.f; }
}

// ---------------------------------------------------------------------------
extern "C" void kernel_launch(void* const* d_in, const int* in_sizes, int n_in,
                              void* d_out, int out_size, void* d_ws, size_t ws_size,
                              hipStream_t stream) {
    const float* ctx   = (const float*)d_in[0];
    const float* query = (const float*)d_in[1];
    const int*   mask  = (const int*)d_in[2];
    const float* noise = (const float*)d_in[3];
    const float* W1    = (const float*)d_in[4];
    const float* b1    = (const float*)d_in[5];
    const float* w2    = (const float*)d_in[6];
    const float* b2    = (const float*)d_in[7];

    float* out_ctx = (float*)d_out;                 // [B, DC]
    float* out_att = (float*)d_out + Bb * DC;       // [B, L]

    char* ws = (char*)d_ws;
    float* score = (float*)ws;                                   // 131072 B
    float* qb    = (float*)(ws + 131072);                        //  65536 B
    unsigned short* w1t  = (unsigned short*)(ws + 196608);       // 1 MiB
    unsigned short* ctxb = (unsigned short*)(ws + 1245184);      // 64 MiB
    const size_t NEED = 1245184 + (size_t)Bb * Ll * DC * 2;      // ~68.4 MB

    if (ws_size >= NEED) {
        // w1t transpose-cvt + zero score/out_ctx (one kernel)
        prep_kernel<<<2176, 256, 0, stream>>>(W1, w1t, score, out_ctx);
        // query @ W1[DC:] + b1 (parallelism-fixed)
        qb_kernel<<<256, 256, 0, stream>>>(query, W1, b1, qb);
        // ctx -> bf16
        cvt_ctx_kernel<<<(Bb * Ll * DC) / (256 * 8), 256, 0, stream>>>(ctx, ctxb);
        // MFMA GEMM + tanh + w2 -> score
        gemm_mfma<<<dim3((Bb * Ll) / 128, Hh / 128), 256, 0, stream>>>(ctxb, w1t, qb, w2, score);
        // sigmoid/mask/noise/scan -> att
        scan_kernel<<<Bb, 64, 0, stream>>>(score, mask, noise, b2, out_att);
        // expected_ctx = att @ ctx  (bf16 ctx)
        ectx_bf16_kernel<<<dim3(1, Ll / 128, Bb), 256, 0, stream>>>(ctxb, out_att, out_ctx);
    } else {
        zero2_kernel<<<(Bb * Ll) / 256, 256, 0, stream>>>(score, out_ctx, Bb * Ll);
        qb_kernel<<<256, 256, 0, stream>>>(query, W1, b1, qb);
        gemm_score_f32<<<dim3((Bb * Ll) / 64, Hh / 64), 256, 0, stream>>>(ctx, W1, qb, w2, score);
        scan_kernel<<<Bb, 64, 0, stream>>>(score, mask, noise, b2, out_att);
        ectx_f32_kernel<<<dim3(DC / 256, Ll / 128, Bb), 256, 0, stream>>>(ctx, out_att, out_ctx);
    }
}